// Round 22
// baseline (154.964 us; speedup 1.0000x reference)
//
#include <hip/hip_runtime.h>
#include <hip/hip_bf16.h>

// MultiHeadAttention: N=2048, H=16, D=128. f32 in, f32 out, int32 mask.
// R23: R22 = 153.2 (best). All kernel-side levers near-exhausted; last
// structural cost is the 3-kernel launch chain. -> TWO launches:
//  K1 "fused": independent block families (no intra-kernel deps):
//    [0,768):    proj (self-contained: W^T staged from f32 in-block via
//                proven R9 pitch-132 transpose + ld2x4; inputs via ld_bf8;
//                frag-major stores from proj4). 128 rows/block.
//    [768,4864): maskpack (transposed) + zero out.
//    [4864,4880): lastb pre-transpose (kept: fixed attn epilogue conflicts).
//  K2 attn: byte-identical to R22 (65.2us, conflicts 131K, FETCH 14.6MB).
// wsW/qkvb deleted. If dTotal < 3us: harness floor -> plateau declared.

#define HN 16
#define NN 2048
#define DD 128

typedef __attribute__((ext_vector_type(8))) short short8;    // MFMA A/B frag
typedef __attribute__((ext_vector_type(4))) short short4v;
typedef __attribute__((ext_vector_type(4))) float float4v;   // 16x16 C/D frag
typedef __attribute__((ext_vector_type(16))) float f32x16;   // 32x32 C/D frag
typedef __attribute__((ext_vector_type(4))) unsigned int uint4v;
typedef __attribute__((ext_vector_type(2))) unsigned int uint2v;

#define CROW(r) ((((r) & 3)) + 8 * ((r) >> 2))   // 32x32 C/D row for reg r

__device__ inline unsigned short f2bf(float f) {
    unsigned int u = __builtin_bit_cast(unsigned int, f);
    unsigned int r = (u + 0x7fffu + ((u >> 16) & 1u)) >> 16;  // RNE
    return (unsigned short)r;
}

// packed f32x2 -> bf16x2 (RNE), gfx950 v_cvt_pk_bf16_f32
__device__ inline unsigned int cvtpk(float lo, float hi) {
    unsigned int w;
    asm("v_cvt_pk_bf16_f32 %0, %1, %2" : "=v"(w) : "v"(lo), "v"(hi));
    return w;
}

// exchange lane-halves
__device__ inline void plswap(unsigned int& x, unsigned int& y) {
#if __has_builtin(__builtin_amdgcn_permlane32_swap)
    typedef int int2v __attribute__((ext_vector_type(2)));
    int2v r = __builtin_amdgcn_permlane32_swap((int)x, (int)y, false, false);
    x = (unsigned int)r[0];
    y = (unsigned int)r[1];
#else
    const unsigned int sx = (unsigned int)__shfl_xor((int)x, 32);
    const unsigned int sy = (unsigned int)__shfl_xor((int)y, 32);
    const bool hiHalf = (threadIdx.x & 32) != 0;
    const unsigned int nx = hiHalf ? sy : x;
    const unsigned int ny = hiHalf ? y : sx;
    x = nx; y = ny;
#endif
}

// 8 contiguous f32 -> bf16 MFMA frag
__device__ inline short8 ld_bf8(const float* __restrict__ p) {
    const float4v a = *(const float4v*)p;
    const float4v b = *(const float4v*)(p + 4);
    short8 r;
    r[0] = (short)f2bf(a[0]); r[1] = (short)f2bf(a[1]);
    r[2] = (short)f2bf(a[2]); r[3] = (short)f2bf(a[3]);
    r[4] = (short)f2bf(b[0]); r[5] = (short)f2bf(b[1]);
    r[6] = (short)f2bf(b[2]); r[7] = (short)f2bf(b[3]);
    return r;
}

// two ds_read_b64 frag load (for odd-pitch LDS arrays; needs 8B align)
__device__ inline short8 ld2x4(const unsigned short* p) {
    const short4v lo = *(const short4v*)p;
    const short4v hi = *(const short4v*)(p + 4);
    short8 r;
    r[0] = lo[0]; r[1] = lo[1]; r[2] = lo[2]; r[3] = lo[3];
    r[4] = hi[0]; r[5] = hi[1]; r[6] = hi[2]; r[7] = hi[3];
    return r;
}

__global__ void sentinel_kernel(float* out, int n) {
    int i = blockIdx.x * 256 + threadIdx.x;
    if (i < n) out[i] = 2.0f;
}

// ---------------------------------------------------------------------------
// Kernel 1: fused prep+proj. Independent block families:
//  [0,768):     proj — t = bx>>8, h = (bx>>4)&15, cb = bx&15; 128 rows/block.
//               W^T staged in-block from f32 (pitch 132); A via ld_bf8;
//               stores: t=0 qA frag-major / t=1 kp row-major / t=2 vpB.
//  [768,4864):  maskpack transposed + zero out (first 1024 of these).
//  [4864,4880): lastb: last[h] -> [e][k] bf16 pre-transpose.
// ---------------------------------------------------------------------------
__global__ __launch_bounds__(256) void fused_kernel(
    const float* __restrict__ q,
    const float* __restrict__ k,
    const float* __restrict__ v,
    const int* __restrict__ mask,
    const float* __restrict__ Qw,
    const float* __restrict__ Kw,
    const float* __restrict__ Vw,
    const float* __restrict__ last,
    unsigned long long* __restrict__ mbT,
    float* __restrict__ out, int out_n,
    unsigned short* __restrict__ ws,
    unsigned short* __restrict__ lastb)
{
    __shared__ __align__(16) unsigned short Wt[128 * 132];  // [e][d], pitch 132
    const int bx = blockIdx.x;
    const int tid = threadIdx.x;

    if (bx < 768) {
        // ---- projection: one (t,h,cb) -> 128 token rows ----
        const int t = bx >> 8, h = (bx >> 4) & 15, cb = bx & 15;
        const float* in = (t == 0) ? q : ((t == 1) ? k : v);
        const float* W  = ((t == 0) ? Qw : ((t == 1) ? Kw : Vw)) + h * DD * DD;
        unsigned short* outp = ws + (size_t)t * (HN * NN * DD) + (size_t)h * (NN * DD);

        for (int idx2 = tid * 2; idx2 < DD * DD; idx2 += 512) {
            const int d = idx2 >> 7, e = idx2 & 127;
            const float2 w2 = *(const float2*)(W + idx2);
            Wt[(e + 0) * 132 + d] = f2bf(w2.x);
            Wt[(e + 1) * 132 + d] = f2bf(w2.y);
        }
        __syncthreads();

        const int wave = tid >> 6, lane = tid & 63;
        const int quad = lane >> 4, l16 = lane & 15;

#pragma unroll 1
        for (int rt = 0; rt < 2; rt++) {
            const int row0 = cb * 128 + rt * 64 + wave * 16;

            float4v acc[8];
#pragma unroll
            for (int c = 0; c < 8; c++) acc[c] = {0.f, 0.f, 0.f, 0.f};

            if (t < 2) {
#pragma unroll
                for (int kk = 0; kk < 4; kk++) {
                    const short8 a = ld_bf8(in + (size_t)(row0 + l16) * DD + kk * 32 + quad * 8);
#pragma unroll
                    for (int c = 0; c < 8; c++) {
                        const short8 b = ld2x4(&Wt[(c * 16 + l16) * 132 + kk * 32 + quad * 8]);
                        acc[c] = __builtin_amdgcn_mfma_f32_16x16x32_bf16(a, b, acc[c], 0, 0, 0);
                    }
                }
                if (t == 0) {
                    // qA[slice = row>>5][kk=c][r32 = row&31][16]
#pragma unroll
                    for (int c = 0; c < 8; c++)
#pragma unroll
                        for (int r = 0; r < 4; r++) {
                            const int row = row0 + quad * 4 + r;
                            outp[(size_t)(((row >> 5) * 8 + c)) * 512 + (row & 31) * 16 + l16]
                                = f2bf(acc[c][r]);
                        }
                } else {
                    // kp row-major [n][d]
#pragma unroll
                    for (int c = 0; c < 8; c++)
#pragma unroll
                        for (int r = 0; r < 4; r++)
                            outp[(size_t)(row0 + quad * 4 + r) * DD + c * 16 + l16] = f2bf(acc[c][r]);
                }
            } else {
                // D[e][token] = vp^T via operand swap
#pragma unroll
                for (int kk = 0; kk < 4; kk++) {
                    const short8 bv = ld_bf8(in + (size_t)(row0 + l16) * DD + kk * 32 + quad * 8);
#pragma unroll
                    for (int c = 0; c < 8; c++) {
                        const short8 aw = ld2x4(&Wt[(c * 16 + l16) * 132 + kk * 32 + quad * 8]);
                        acc[c] = __builtin_amdgcn_mfma_f32_16x16x32_bf16(aw, bv, acc[c], 0, 0, 0);
                    }
                }
                // vpB[jb16 = row0/16][d][j16 = l16]
#pragma unroll
                for (int c = 0; c < 8; c++)
#pragma unroll
                    for (int r = 0; r < 4; r++) {
                        const int d = c * 16 + quad * 4 + r;
                        outp[(size_t)(row0 >> 4) * 2048 + d * 16 + l16] = f2bf(acc[c][r]);
                    }
            }
        }
    } else if (bx < 4864) {
        // ---- maskpack (4 words per wave) + fused zero ----
        const int mbx = bx - 768;               // 0..4095
        const int wgrp = mbx * 4 + (tid >> 6);
        const int lane = tid & 63;
        const int word0 = wgrp * 4;             // 4 consecutive words, same row
        const int i = word0 >> 5;               // row
        const int w = word0 & 31;               // word within row
        const int* row = mask + (size_t)i * NN + w * 64;
        unsigned long long b[4];
#pragma unroll
        for (int c = 0; c < 4; c++)
            b[c] = __ballot(row[c * 64 + lane] != 0);
        if (lane == 0) {
#pragma unroll
            for (int c = 0; c < 4; c++) mbT[(size_t)(w + c) * NN + i] = b[c];
        }
        const int z = mbx * 256 + tid;
        if (z < out_n) out[z] = 0.f;
    } else {
        // ---- lastb: last[h] -> [e][k] bf16 pre-transpose ----
        const int h = bx - 4864;                // 0..15
        const float* W = last + (size_t)h * DD * DD;
        unsigned short* o = lastb + (size_t)h * DD * DD;

        for (int idx2 = tid * 2; idx2 < DD * DD; idx2 += 512) {
            const int d = idx2 >> 7, e = idx2 & 127;
            const float2 w2 = *(const float2*)(W + idx2);
            Wt[(e + 0) * 132 + d] = f2bf(w2.x);
            Wt[(e + 1) * 132 + d] = f2bf(w2.y);
        }
        __syncthreads();
        for (int idx8 = tid * 8; idx8 < DD * DD; idx8 += 2048) {
            const int e = idx8 >> 7, d = idx8 & 127;
            *(short8*)(o + idx8) = ld2x4(&Wt[e * 132 + d]);
        }
    }
}

// ---------------------------------------------------------------------------
// Kernel 2: flash attention + FUSED final GEMM (R22, proven). XCD-clustered
// 1D grid(512). lastT staged from pre-transposed bf16 (conflict-free).
// ---------------------------------------------------------------------------
__global__ __launch_bounds__(256, 2) void attn_kernel(
    unsigned short* __restrict__ ws,
    const unsigned long long* __restrict__ mbT,
    const unsigned short* __restrict__ lastb,   // [h][e][k] bf16, pre-transposed
    float* __restrict__ outp)
{
    __shared__ __align__(16) float obuf[2 * 128 * 33];      // (ig, d, i) pitch 33
    __shared__ __align__(16) unsigned short lastT[128 * 132]; // [e][k] bf16
    __shared__ float lbuf[192];                             // row sums / inv

    const int bid = blockIdx.x;
    const int xcd = bid & 7;
    const int h  = xcd + 8 * (bid >> 8);     // heads {xcd, xcd+8} per XCD
    const int ib = (bid >> 3) & 31;
    const int tid = threadIdx.x;
    const int wave = tid >> 6, lane = tid & 63;
    const int ig = wave >> 1;        // i-group: 0 -> rows 0..31, 1 -> 32..63
    const int h2 = wave & 1;         // j-half of each 64-j tile
    const int l31 = lane & 31;
    const int hi = lane >> 5;        // lane half

    const unsigned short* qA  = ws + (size_t)h * (NN * DD);                          // frag-major
    const unsigned short* kp  = ws + (size_t)(HN * NN * DD) + (size_t)h * (NN * DD); // row-major
    const unsigned short* vpB = ws + (size_t)(2 * HN * NN * DD) + (size_t)h * (NN * DD); // frag-major

    const int i0 = ib * 64;
    const float scale = 0.022097086912079612f;  // 1/sqrt(2048)

    // Stage pre-transposed last -> lastT (coalesced; conflict-free writes).
    {
        const unsigned short* lastBh = lastb + (size_t)h * DD * DD;
#pragma unroll
        for (int it = 0; it < 8; it++) {
            const int idx8 = tid * 8 + it * 2048;
            const int e = idx8 >> 7, kk = idx8 & 127;
            const short8 x = *(const short8*)(lastBh + idx8);
            short4v lo, hi4;
            lo[0] = x[0]; lo[1] = x[1]; lo[2] = x[2]; lo[3] = x[3];
            hi4[0] = x[4]; hi4[1] = x[5]; hi4[2] = x[6]; hi4[3] = x[7];
            *(short4v*)(&lastT[e * 132 + kk]) = lo;
            *(short4v*)(&lastT[e * 132 + kk + 4]) = hi4;
        }
    }

    // kp B-frags (B[k=d][n=i], lane&31 = i): loaded once.
    short8 kpf[8];
    {
        const int row = i0 + ig * 32 + l31;
#pragma unroll
        for (int kk = 0; kk < 8; kk++)
            kpf[kk] = *(const short8*)(kp + (size_t)row * DD + kk * 16 + hi * 8);
    }

    // per-lane base pointers into the frag-major arrays
    const unsigned short* qbase = qA + l31 * 16 + hi * 8;   // + (jb*8+kk)*512
    const unsigned short* vbase = vpB + l31 * 16 + hi * 8;  // + jb16*2048 + dt*512

    f32x16 o[4];
#pragma unroll
    for (int dt = 0; dt < 4; dt++)
#pragma unroll
        for (int r = 0; r < 16; r++) o[dt][r] = 0.f;
    float lacc = 0.f;

    short8 qfA[8], qfB[8];

#define QLD(QF, JT) do {                                                        \
        const unsigned short* p_ = qbase + (size_t)(((JT) * 2 + h2) * 8) * 512; \
        _Pragma("unroll")                                                       \
        for (int kk = 0; kk < 8; kk++)                                          \
            QF[kk] = *(const short8*)(p_ + kk * 512);                           \
    } while (0)

    // T[j][i] = sum_d qp[j][d]*kp[i][d]: A = qf (regs), B = kpf (regs).
    auto COMPUTE = [&](const short8 (&qf)[8], int jt) {
        short8 vf[8];
#pragma unroll
        for (int ks = 0; ks < 2; ks++)
#pragma unroll
            for (int dt = 0; dt < 4; dt++)
                vf[ks * 4 + dt] = *(const short8*)(vbase
                    + (size_t)(jt * 4 + h2 * 2 + ks) * 2048 + dt * 512);
        const unsigned long long mrow = mbT[(size_t)jt * NN + i0 + ig * 32 + l31];
        const unsigned int m2 = (unsigned int)(mrow >> (h2 * 32 + hi * 4));

        f32x16 s;
#pragma unroll
        for (int r = 0; r < 16; r++) s[r] = 0.f;
        __builtin_amdgcn_s_setprio(1);
#pragma unroll
        for (int kk = 0; kk < 8; kk++)
            s = __builtin_amdgcn_mfma_f32_32x32x16_bf16(qf[kk], kpf[kk], s, 0, 0, 0);
        __builtin_amdgcn_s_setprio(0);

        // static-max softmax: p = exp(s*scale - 5) (masked -> exp(-50) ~ 0)
#pragma unroll
        for (int r = 0; r < 16; r++) {
            const float x = ((m2 >> CROW(r)) & 1u) ? fmaf(s[r], scale, -5.0f) : -50.0f;
            s[r] = __expf(x);
        }
        float ls = (((s[0] + s[1]) + (s[2] + s[3])) + ((s[4] + s[5]) + (s[6] + s[7])))
                 + (((s[8] + s[9]) + (s[10] + s[11])) + ((s[12] + s[13]) + (s[14] + s[15])));
        ls += __shfl_xor(ls, 32);
        lacc += ls;

        // T12 repack: P -> two PV A-frags (lane = i, k = j), zero LDS.
        short8 pa[2];
#pragma unroll
        for (int ks = 0; ks < 2; ks++) {
            const int b = ks * 8;
            unsigned int x0 = cvtpk(s[b + 0], s[b + 1]);
            unsigned int y0 = cvtpk(s[b + 4], s[b + 5]);
            unsigned int x1 = cvtpk(s[b + 2], s[b + 3]);
            unsigned int y1 = cvtpk(s[b + 6], s[b + 7]);
            plswap(x0, y0);
            plswap(x1, y1);
            uint4v w; w[0] = x0; w[1] = x1; w[2] = y0; w[3] = y1;
            pa[ks] = __builtin_bit_cast(short8, w);
        }

        // O[i][d] += P · vp
        __builtin_amdgcn_s_setprio(1);
#pragma unroll
        for (int ks = 0; ks < 2; ks++)
#pragma unroll
            for (int dt = 0; dt < 4; dt++)
                o[dt] = __builtin_amdgcn_mfma_f32_32x32x16_bf16(pa[ks], vf[ks * 4 + dt], o[dt], 0, 0, 0);
        __builtin_amdgcn_s_setprio(0);
    };

    QLD(qfA, 0);
#pragma unroll 1
    for (int jt = 0; jt < 32; jt += 2) {
        QLD(qfB, jt + 1);
        COMPUTE(qfA, jt);
        if (jt + 2 < 32) QLD(qfA, jt + 2);
        COMPUTE(qfB, jt + 1);
    }
#undef QLD

    // ---- Epilogue phase 1: h2==1 publishes partials ((d,i) layout, pitch 33).
    if (h2 == 1) {
#pragma unroll
        for (int dt = 0; dt < 4; dt++)
#pragma unroll
            for (int r = 0; r < 16; r++)
                obuf[(size_t)(ig * 128 + dt * 32 + l31) * 33 + CROW(r) + hi * 4] = o[dt][r];
        if (hi == 0) lbuf[ig * 32 + l31] = lacc;
    }
    __syncthreads();   // also fences the lastT staging

    // ---- Phase 2: h2==0 combines, normalizes, writes back combined O.
    if (h2 == 0) {
        const float lt = lacc + lbuf[ig * 32 + l31];
        const float inv = (lt > 0.f) ? (1.0f / lt) : 0.f;
        if (hi == 0) lbuf[64 + ig * 32 + l31] = inv;  // same-wave RAW, lgkm-ordered
#pragma unroll
        for (int dt = 0; dt < 4; dt++)
#pragma unroll
            for (int r = 0; r < 16; r++) {
                const int row = CROW(r) + hi * 4;     // i_local 0..31
                const size_t oi = (size_t)(ig * 128 + dt * 32 + l31) * 33 + row;
                obuf[oi] = (o[dt][r] + obuf[oi]) * lbuf[64 + ig * 32 + row];
            }
    }
    __syncthreads();

    // ---- Phase 3: fused last-GEMM. A-frags from obuf (lane = i, k = d),
    // B-frags from lastT (lane = e, pitch-132 ~2-way). 2 e-blocks per wave.
    short8 af[8];
#pragma unroll
    for (int kk = 0; kk < 8; kk++) {
        const float* ob = &obuf[(size_t)(ig * 128 + kk * 16 + hi * 8) * 33 + l31];
        uint4v w;
        w[0] = cvtpk(ob[0 * 33], ob[1 * 33]);
        w[1] = cvtpk(ob[2 * 33], ob[3 * 33]);
        w[2] = cvtpk(ob[4 * 33], ob[5 * 33]);
        w[3] = cvtpk(ob[6 * 33], ob[7 * 33]);
        af[kk] = __builtin_bit_cast(short8, w);
    }
    f32x16 acc2[2];
#pragma unroll
    for (int ebx = 0; ebx < 2; ebx++)
#pragma unroll
        for (int r = 0; r < 16; r++) acc2[ebx][r] = 0.f;
#pragma unroll
    for (int kk = 0; kk < 8; kk++) {
#pragma unroll
        for (int ebx = 0; ebx < 2; ebx++) {
            const short8 bf = ld2x4(&lastT[(size_t)((h2 * 2 + ebx) * 32 + l31) * 132
                                           + kk * 16 + hi * 8]);
            acc2[ebx] = __builtin_amdgcn_mfma_f32_32x32x16_bf16(af[kk], bf, acc2[ebx], 0, 0, 0);
        }
    }
#pragma unroll
    for (int ebx = 0; ebx < 2; ebx++)
#pragma unroll
        for (int r = 0; r < 16; r++)
            atomicAdd(&outp[(size_t)(i0 + ig * 32 + CROW(r) + 4 * hi) * DD
                            + (h2 * 2 + ebx) * 32 + l31],
                      acc2[ebx][r]);
}

extern "C" void kernel_launch(void* const* d_in, const int* in_sizes, int n_in,
                              void* d_out, int out_size, void* d_ws, size_t ws_size,
                              hipStream_t stream)
{
    const float* q    = (const float*)d_in[0];
    const float* k    = (const float*)d_in[1];
    const float* v    = (const float*)d_in[2];
    const int*   mask = (const int*)d_in[3];
    const float* Qw   = (const float*)d_in[4];
    const float* Kw   = (const float*)d_in[5];
    const float* Vw   = (const float*)d_in[6];
    const float* last = (const float*)d_in[7];
    unsigned short* ws  = (unsigned short*)d_ws;
    float* out = (float*)d_out;

    // ws (bf16): qA[16*2048*128] | kp[...] | vpB[16][...] | ao-region
    // (hosts lastb 256K shorts) | mbT[32][2048] u64 (bitpacked mask)
    const size_t shorts_main = (size_t)4 * HN * NN * DD;
    const size_t mb_bytes = (size_t)NN * (NN / 64) * 8;
    const size_t needed = shorts_main * sizeof(unsigned short) + mb_bytes;
    if (ws_size < needed) {
        sentinel_kernel<<<(out_size + 255) / 256, 256, 0, stream>>>(out, out_size);
        return;
    }
    unsigned long long* mbT = (unsigned long long*)(ws + shorts_main);
    unsigned short* lastb = ws + (size_t)3 * HN * NN * DD;   // in ao region

    fused_kernel<<<dim3(768 + 4096 + 16), 256, 0, stream>>>(
        q, k, v, mask, Qw, Kw, Vw, last, mbT, out, out_size, ws, lastb);
    attn_kernel<<<dim3(512), 256, 0, stream>>>(ws, mbT, lastb, out);
}

// Round 23
// 152.540 us; speedup vs baseline: 1.0159x; 1.0159x over previous
//
#include <hip/hip_runtime.h>
#include <hip/hip_bf16.h>

// MultiHeadAttention: N=2048, H=16, D=128. f32 in, f32 out, int32 mask.
// R24 FINAL: resubmit of R22, the best-verified configuration (153.2us).
// Session 337 -> 153us (2.2x). Structure:
//  prep:  maskpack->mbT (transposed bits) + out-zero + W^T/last^T bf16 +
//         qkv->bf16 (all coalesced, one launch).
//  proj6: per-(64rows,head,tensor) block, 6 blocks/CU; W^T from global
//         scratch staged to LDS conflict-free; frag-major outputs
//         (qA slices / kp rows / vpB frags) so attn needs NO LDS staging.
//  attn:  XCD-clustered (FETCH 70->14.6MB), frag-major reg-resident main
//         loop (0 LDS ops, 0 barriers), static-max softmax via T12
//         in-register repack, fused final GEMM epilogue (atomicAdd into
//         pre-zeroed out).
// Plateau: attn latency-bound at 2 waves/SIMD (reg-pinned, spill-proven);
// prep/proj at compute floor; residual is launch/reset floor.

#define HN 16
#define NN 2048
#define DD 128

typedef __attribute__((ext_vector_type(8))) short short8;    // MFMA A/B frag
typedef __attribute__((ext_vector_type(4))) short short4v;
typedef __attribute__((ext_vector_type(4))) float float4v;   // 16x16 C/D frag
typedef __attribute__((ext_vector_type(16))) float f32x16;   // 32x32 C/D frag
typedef __attribute__((ext_vector_type(4))) unsigned int uint4v;
typedef __attribute__((ext_vector_type(2))) unsigned int uint2v;

#define CROW(r) ((((r) & 3)) + 8 * ((r) >> 2))   // 32x32 C/D row for reg r

__device__ inline unsigned short f2bf(float f) {
    unsigned int u = __builtin_bit_cast(unsigned int, f);
    unsigned int r = (u + 0x7fffu + ((u >> 16) & 1u)) >> 16;  // RNE
    return (unsigned short)r;
}

// packed f32x2 -> bf16x2 (RNE), gfx950 v_cvt_pk_bf16_f32
__device__ inline unsigned int cvtpk(float lo, float hi) {
    unsigned int w;
    asm("v_cvt_pk_bf16_f32 %0, %1, %2" : "=v"(w) : "v"(lo), "v"(hi));
    return w;
}

// exchange lane-halves
__device__ inline void plswap(unsigned int& x, unsigned int& y) {
#if __has_builtin(__builtin_amdgcn_permlane32_swap)
    typedef int int2v __attribute__((ext_vector_type(2)));
    int2v r = __builtin_amdgcn_permlane32_swap((int)x, (int)y, false, false);
    x = (unsigned int)r[0];
    y = (unsigned int)r[1];
#else
    const unsigned int sx = (unsigned int)__shfl_xor((int)x, 32);
    const unsigned int sy = (unsigned int)__shfl_xor((int)y, 32);
    const bool hiHalf = (threadIdx.x & 32) != 0;
    const unsigned int nx = hiHalf ? sy : x;
    const unsigned int ny = hiHalf ? y : sx;
    x = nx; y = ny;
#endif
}

// two ds_read_b64 frag load (for odd-pitch LDS arrays; needs 8B align)
__device__ inline short8 ld2x4(const unsigned short* p) {
    const short4v lo = *(const short4v*)p;
    const short4v hi = *(const short4v*)(p + 4);
    short8 r;
    r[0] = lo[0]; r[1] = lo[1]; r[2] = lo[2]; r[3] = lo[3];
    r[4] = hi[0]; r[5] = hi[1]; r[6] = hi[2]; r[7] = hi[3];
    return r;
}

__global__ void sentinel_kernel(float* out, int n) {
    int i = blockIdx.x * 256 + threadIdx.x;
    if (i < n) out[i] = 2.0f;
}

// ---------------------------------------------------------------------------
// Kernel P: fused prep.
// Blocks 0..4095: mask bitpack (transposed) + zero out (bx<1024).
// Blocks 4096..4159: W/last transpose+convert -> wsW (t=0..3; t==3 is last).
// Blocks 4160..4255: q/k/v f32 -> bf16 (coalesced) -> qkvb.
// ---------------------------------------------------------------------------
__global__ __launch_bounds__(256) void prep_kernel(
    const int* __restrict__ mask,
    unsigned long long* __restrict__ mbT,
    float* __restrict__ out, int out_n,
    const float* __restrict__ Qw,
    const float* __restrict__ Kw,
    const float* __restrict__ Vw,
    const float* __restrict__ last,
    const float* __restrict__ q,
    const float* __restrict__ k,
    const float* __restrict__ v,
    unsigned short* __restrict__ wsW,
    unsigned short* __restrict__ qkvb)
{
    __shared__ __align__(16) unsigned short Wt[128 * 132];
    const int bx = blockIdx.x;
    const int tid = threadIdx.x;

    if (bx < 4096) {
        // ---- maskpack (4 words per wave; wgrp 0..16383 = all words) ----
        const int wgrp = bx * 4 + (tid >> 6);
        const int lane = tid & 63;
        const int word0 = wgrp * 4;             // 4 consecutive words, same row
        const int i = word0 >> 5;               // row
        const int w = word0 & 31;               // word within row
        const int* row = mask + (size_t)i * NN + w * 64;
        unsigned long long b[4];
#pragma unroll
        for (int c = 0; c < 4; c++)
            b[c] = __ballot(row[c * 64 + lane] != 0);
        if (lane == 0) {
#pragma unroll
            for (int c = 0; c < 4; c++) mbT[(size_t)(w + c) * NN + i] = b[c];
        }
        // fused zero of out (bx<1024 covers out_n = 2048*128 exactly)
        const int z = bx * 256 + tid;
        if (z < out_n) out[z] = 0.f;
    } else if (bx < 4160) {
        // ---- wprep: one (t,h) per block; t==3 is `last` (per-head slice) ----
        const int idx = bx - 4096;              // 0..63
        const int h = idx & 15, t = idx >> 4;   // t in 0..3
        const float* W = (t == 0) ? (Qw + h * DD * DD)
                       : (t == 1) ? (Kw + h * DD * DD)
                       : (t == 2) ? (Vw + h * DD * DD)
                                  : (last + (size_t)h * DD * DD);
        unsigned short* o = wsW + ((size_t)t * HN + h) * DD * DD;

        for (int idx2 = tid * 2; idx2 < DD * DD; idx2 += 512) {
            const int d = idx2 >> 7, e = idx2 & 127;
            const float2 w2 = *(const float2*)(W + idx2);
            Wt[(e + 0) * 132 + d] = f2bf(w2.x);
            Wt[(e + 1) * 132 + d] = f2bf(w2.y);
        }
        __syncthreads();
        for (int idx8 = tid * 8; idx8 < DD * DD; idx8 += 2048) {
            const int e = idx8 >> 7, d = idx8 & 127;
            *(short8*)(o + idx8) = ld2x4(&Wt[e * 132 + d]);
        }
    } else {
        // ---- qkv -> bf16: 96 blocks (32 per tensor), fully coalesced ----
        const int idx = bx - 4160;              // 0..95
        const int t = idx >> 5, chunk = idx & 31;
        const float* in = (t == 0) ? q : ((t == 1) ? k : v);
        const float* src = in + (size_t)chunk * 8192;
        unsigned short* dst = qkvb + (size_t)t * (NN * DD) + (size_t)chunk * 8192;
#pragma unroll
        for (int it = 0; it < 8; it++) {
            const int e4 = it * 1024 + tid * 4;
            const float4v x = *(const float4v*)(src + e4);
            uint2v w;
            w[0] = cvtpk(x[0], x[1]);
            w[1] = cvtpk(x[2], x[3]);
            *(uint2v*)(dst + e4) = w;
        }
    }
}

// ---------------------------------------------------------------------------
// Kernel A: projections v6. grid = (32 row-tiles, 16 heads, 3 tensors)
// = 1536 blocks (6/CU): single 64-row tile per block for 2x TLP on the
// serial global-load chain. Input pre-converted bf16 (qkvb).
// t=0 -> qA frag-major [slice][kk][32][16]; t=1 -> kp row-major;
// t=2 -> vpB frag-major [j16][d][16].
// ---------------------------------------------------------------------------
__global__ __launch_bounds__(256) void proj6_kernel(
    const unsigned short* __restrict__ qkvb,
    const unsigned short* __restrict__ wsW,
    unsigned short* __restrict__ ws)
{
    __shared__ __align__(16) unsigned short Wt[128 * 136];  // [e][d], pitch 136
    const int t = blockIdx.z, h = blockIdx.y, cb = blockIdx.x;
    const int tid = threadIdx.x;
    const unsigned short* inb = qkvb + (size_t)t * (NN * DD);
    const unsigned short* WTg = wsW + ((size_t)t * HN + h) * DD * DD;
    unsigned short* out = ws + (size_t)t * (HN * NN * DD) + (size_t)h * (NN * DD);

#pragma unroll
    for (int it = 0; it < 8; it++) {
        const int idx8 = tid * 8 + it * 2048;
        const int row = idx8 >> 7, col = idx8 & 127;
        *(short8*)(&Wt[row * 136 + col]) = *(const short8*)(WTg + idx8);
    }
    __syncthreads();

    const int wave = tid >> 6, lane = tid & 63;
    const int quad = lane >> 4, l16 = lane & 15;
    const int row0 = cb * 64 + wave * 16;

    float4v acc[8];
#pragma unroll
    for (int c = 0; c < 8; c++) acc[c] = {0.f, 0.f, 0.f, 0.f};

    if (t < 2) {
#pragma unroll
        for (int kk = 0; kk < 4; kk++) {
            const short8 a = *(const short8*)(inb + (size_t)(row0 + l16) * DD + kk * 32 + quad * 8);
#pragma unroll
            for (int c = 0; c < 8; c++) {
                const short8 b = *(const short8*)(&Wt[(c * 16 + l16) * 136 + kk * 32 + quad * 8]);
                acc[c] = __builtin_amdgcn_mfma_f32_16x16x32_bf16(a, b, acc[c], 0, 0, 0);
            }
        }
        if (t == 0) {
            // qA[slice = row>>5][kk=c][r32 = row&31][16]
#pragma unroll
            for (int c = 0; c < 8; c++)
#pragma unroll
                for (int r = 0; r < 4; r++) {
                    const int row = row0 + quad * 4 + r;
                    out[(size_t)(((row >> 5) * 8 + c)) * 512 + (row & 31) * 16 + l16]
                        = f2bf(acc[c][r]);
                }
        } else {
            // kp row-major [n][d]
#pragma unroll
            for (int c = 0; c < 8; c++)
#pragma unroll
                for (int r = 0; r < 4; r++)
                    out[(size_t)(row0 + quad * 4 + r) * DD + c * 16 + l16] = f2bf(acc[c][r]);
        }
    } else {
        // D[e][token] = vp^T via operand swap
#pragma unroll
        for (int kk = 0; kk < 4; kk++) {
            const short8 bv = *(const short8*)(inb + (size_t)(row0 + l16) * DD + kk * 32 + quad * 8);
#pragma unroll
            for (int c = 0; c < 8; c++) {
                const short8 aw = *(const short8*)(&Wt[(c * 16 + l16) * 136 + kk * 32 + quad * 8]);
                acc[c] = __builtin_amdgcn_mfma_f32_16x16x32_bf16(aw, bv, acc[c], 0, 0, 0);
            }
        }
        // vpB[jb16 = row0/16][d][j16 = l16]
#pragma unroll
        for (int c = 0; c < 8; c++)
#pragma unroll
            for (int r = 0; r < 4; r++) {
                const int d = c * 16 + quad * 4 + r;
                out[(size_t)(row0 >> 4) * 2048 + d * 16 + l16] = f2bf(acc[c][r]);
            }
    }
}

// ---------------------------------------------------------------------------
// Kernel B: flash attention + FUSED final GEMM. XCD-clustered 1D grid(512).
// lastT staged from PRE-TRANSPOSED bf16 (coalesced, conflict-free).
// Main loop: frag-major operands, no LDS/barriers, Q reg-dbuf 1 tile ahead.
// ---------------------------------------------------------------------------
__global__ __launch_bounds__(256, 2) void attn_kernel(
    unsigned short* __restrict__ ws,
    const unsigned long long* __restrict__ mbT,
    const unsigned short* __restrict__ lastb,   // [h][e][k] bf16, pre-transposed
    float* __restrict__ outp)
{
    __shared__ __align__(16) float obuf[2 * 128 * 33];      // (ig, d, i) pitch 33
    __shared__ __align__(16) unsigned short lastT[128 * 132]; // [e][k] bf16
    __shared__ float lbuf[192];                             // row sums / inv

    const int bid = blockIdx.x;
    const int xcd = bid & 7;
    const int h  = xcd + 8 * (bid >> 8);     // heads {xcd, xcd+8} per XCD
    const int ib = (bid >> 3) & 31;
    const int tid = threadIdx.x;
    const int wave = tid >> 6, lane = tid & 63;
    const int ig = wave >> 1;        // i-group: 0 -> rows 0..31, 1 -> 32..63
    const int h2 = wave & 1;         // j-half of each 64-j tile
    const int l31 = lane & 31;
    const int hi = lane >> 5;        // lane half

    const unsigned short* qA  = ws + (size_t)h * (NN * DD);                          // frag-major
    const unsigned short* kp  = ws + (size_t)(HN * NN * DD) + (size_t)h * (NN * DD); // row-major
    const unsigned short* vpB = ws + (size_t)(2 * HN * NN * DD) + (size_t)h * (NN * DD); // frag-major

    const int i0 = ib * 64;
    const float scale = 0.022097086912079612f;  // 1/sqrt(2048)

    // Stage pre-transposed last -> lastT (coalesced; conflict-free writes).
    {
        const unsigned short* lastBh = lastb + (size_t)h * DD * DD;
#pragma unroll
        for (int it = 0; it < 8; it++) {
            const int idx8 = tid * 8 + it * 2048;
            const int e = idx8 >> 7, kk = idx8 & 127;
            const short8 x = *(const short8*)(lastBh + idx8);
            short4v lo, hi4;
            lo[0] = x[0]; lo[1] = x[1]; lo[2] = x[2]; lo[3] = x[3];
            hi4[0] = x[4]; hi4[1] = x[5]; hi4[2] = x[6]; hi4[3] = x[7];
            *(short4v*)(&lastT[e * 132 + kk]) = lo;
            *(short4v*)(&lastT[e * 132 + kk + 4]) = hi4;
        }
    }

    // kp B-frags (B[k=d][n=i], lane&31 = i): loaded once.
    short8 kpf[8];
    {
        const int row = i0 + ig * 32 + l31;
#pragma unroll
        for (int kk = 0; kk < 8; kk++)
            kpf[kk] = *(const short8*)(kp + (size_t)row * DD + kk * 16 + hi * 8);
    }

    // per-lane base pointers into the frag-major arrays
    const unsigned short* qbase = qA + l31 * 16 + hi * 8;   // + (jb*8+kk)*512
    const unsigned short* vbase = vpB + l31 * 16 + hi * 8;  // + jb16*2048 + dt*512

    f32x16 o[4];
#pragma unroll
    for (int dt = 0; dt < 4; dt++)
#pragma unroll
        for (int r = 0; r < 16; r++) o[dt][r] = 0.f;
    float lacc = 0.f;

    short8 qfA[8], qfB[8];

#define QLD(QF, JT) do {                                                        \
        const unsigned short* p_ = qbase + (size_t)(((JT) * 2 + h2) * 8) * 512; \
        _Pragma("unroll")                                                       \
        for (int kk = 0; kk < 8; kk++)                                          \
            QF[kk] = *(const short8*)(p_ + kk * 512);                           \
    } while (0)

    // T[j][i] = sum_d qp[j][d]*kp[i][d]: A = qf (regs), B = kpf (regs).
    auto COMPUTE = [&](const short8 (&qf)[8], int jt) {
        short8 vf[8];
#pragma unroll
        for (int ks = 0; ks < 2; ks++)
#pragma unroll
            for (int dt = 0; dt < 4; dt++)
                vf[ks * 4 + dt] = *(const short8*)(vbase
                    + (size_t)(jt * 4 + h2 * 2 + ks) * 2048 + dt * 512);
        const unsigned long long mrow = mbT[(size_t)jt * NN + i0 + ig * 32 + l31];
        const unsigned int m2 = (unsigned int)(mrow >> (h2 * 32 + hi * 4));

        f32x16 s;
#pragma unroll
        for (int r = 0; r < 16; r++) s[r] = 0.f;
        __builtin_amdgcn_s_setprio(1);
#pragma unroll
        for (int kk = 0; kk < 8; kk++)
            s = __builtin_amdgcn_mfma_f32_32x32x16_bf16(qf[kk], kpf[kk], s, 0, 0, 0);
        __builtin_amdgcn_s_setprio(0);

        // static-max softmax: p = exp(s*scale - 5) (masked -> exp(-50) ~ 0)
#pragma unroll
        for (int r = 0; r < 16; r++) {
            const float x = ((m2 >> CROW(r)) & 1u) ? fmaf(s[r], scale, -5.0f) : -50.0f;
            s[r] = __expf(x);
        }
        float ls = (((s[0] + s[1]) + (s[2] + s[3])) + ((s[4] + s[5]) + (s[6] + s[7])))
                 + (((s[8] + s[9]) + (s[10] + s[11])) + ((s[12] + s[13]) + (s[14] + s[15])));
        ls += __shfl_xor(ls, 32);
        lacc += ls;

        // T12 repack: P -> two PV A-frags (lane = i, k = j), zero LDS.
        short8 pa[2];
#pragma unroll
        for (int ks = 0; ks < 2; ks++) {
            const int b = ks * 8;
            unsigned int x0 = cvtpk(s[b + 0], s[b + 1]);
            unsigned int y0 = cvtpk(s[b + 4], s[b + 5]);
            unsigned int x1 = cvtpk(s[b + 2], s[b + 3]);
            unsigned int y1 = cvtpk(s[b + 6], s[b + 7]);
            plswap(x0, y0);
            plswap(x1, y1);
            uint4v w; w[0] = x0; w[1] = x1; w[2] = y0; w[3] = y1;
            pa[ks] = __builtin_bit_cast(short8, w);
        }

        // O[i][d] += P · vp
        __builtin_amdgcn_s_setprio(1);
#pragma unroll
        for (int ks = 0; ks < 2; ks++)
#pragma unroll
            for (int dt = 0; dt < 4; dt++)
                o[dt] = __builtin_amdgcn_mfma_f32_32x32x16_bf16(pa[ks], vf[ks * 4 + dt], o[dt], 0, 0, 0);
        __builtin_amdgcn_s_setprio(0);
    };

    QLD(qfA, 0);
#pragma unroll 1
    for (int jt = 0; jt < 32; jt += 2) {
        QLD(qfB, jt + 1);
        COMPUTE(qfA, jt);
        if (jt + 2 < 32) QLD(qfA, jt + 2);
        COMPUTE(qfB, jt + 1);
    }
#undef QLD

    // ---- Epilogue phase 1: h2==1 publishes partials ((d,i) layout, pitch 33).
    if (h2 == 1) {
#pragma unroll
        for (int dt = 0; dt < 4; dt++)
#pragma unroll
            for (int r = 0; r < 16; r++)
                obuf[(size_t)(ig * 128 + dt * 32 + l31) * 33 + CROW(r) + hi * 4] = o[dt][r];
        if (hi == 0) lbuf[ig * 32 + l31] = lacc;
    }
    __syncthreads();   // also fences the lastT staging

    // ---- Phase 2: h2==0 combines, normalizes, writes back combined O.
    if (h2 == 0) {
        const float lt = lacc + lbuf[ig * 32 + l31];
        const float inv = (lt > 0.f) ? (1.0f / lt) : 0.f;
        if (hi == 0) lbuf[64 + ig * 32 + l31] = inv;  // same-wave RAW, lgkm-ordered
#pragma unroll
        for (int dt = 0; dt < 4; dt++)
#pragma unroll
            for (int r = 0; r < 16; r++) {
                const int row = CROW(r) + hi * 4;     // i_local 0..31
                const size_t oi = (size_t)(ig * 128 + dt * 32 + l31) * 33 + row;
                obuf[oi] = (o[dt][r] + obuf[oi]) * lbuf[64 + ig * 32 + row];
            }
    }
    __syncthreads();

    // ---- Phase 3: fused last-GEMM. A-frags from obuf (lane = i, k = d),
    // B-frags from lastT (lane = e, pitch-132 ~2-way). 2 e-blocks per wave.
    short8 af[8];
#pragma unroll
    for (int kk = 0; kk < 8; kk++) {
        const float* ob = &obuf[(size_t)(ig * 128 + kk * 16 + hi * 8) * 33 + l31];
        uint4v w;
        w[0] = cvtpk(ob[0 * 33], ob[1 * 33]);
        w[1] = cvtpk(ob[2 * 33], ob[3 * 33]);
        w[2] = cvtpk(ob[4 * 33], ob[5 * 33]);
        w[3] = cvtpk(ob[6 * 33], ob[7 * 33]);
        af[kk] = __builtin_bit_cast(short8, w);
    }
    f32x16 acc2[2];
#pragma unroll
    for (int ebx = 0; ebx < 2; ebx++)
#pragma unroll
        for (int r = 0; r < 16; r++) acc2[ebx][r] = 0.f;
#pragma unroll
    for (int kk = 0; kk < 8; kk++) {
#pragma unroll
        for (int ebx = 0; ebx < 2; ebx++) {
            const short8 bf = ld2x4(&lastT[(size_t)((h2 * 2 + ebx) * 32 + l31) * 132
                                           + kk * 16 + hi * 8]);
            acc2[ebx] = __builtin_amdgcn_mfma_f32_32x32x16_bf16(af[kk], bf, acc2[ebx], 0, 0, 0);
        }
    }
#pragma unroll
    for (int ebx = 0; ebx < 2; ebx++)
#pragma unroll
        for (int r = 0; r < 16; r++)
            atomicAdd(&outp[(size_t)(i0 + ig * 32 + CROW(r) + 4 * hi) * DD
                            + (h2 * 2 + ebx) * 32 + l31],
                      acc2[ebx][r]);
}

extern "C" void kernel_launch(void* const* d_in, const int* in_sizes, int n_in,
                              void* d_out, int out_size, void* d_ws, size_t ws_size,
                              hipStream_t stream)
{
    const float* q    = (const float*)d_in[0];
    const float* k    = (const float*)d_in[1];
    const float* v    = (const float*)d_in[2];
    const int*   mask = (const int*)d_in[3];
    const float* Qw   = (const float*)d_in[4];
    const float* Kw   = (const float*)d_in[5];
    const float* Vw   = (const float*)d_in[6];
    const float* last = (const float*)d_in[7];
    unsigned short* ws  = (unsigned short*)d_ws;
    float* out = (float*)d_out;

    // ws (bf16): qA[16*2048*128] | kp[...] | vpB[16][...] | ao-region
    // (wsW: 4 tensors x 16 heads x 16K shorts = 2MB; qkvb: 1.5MB) | mbT u64
    const size_t shorts_main = (size_t)4 * HN * NN * DD;
    const size_t mb_bytes = (size_t)NN * (NN / 64) * 8;
    const size_t needed = shorts_main * sizeof(unsigned short) + mb_bytes;
    if (ws_size < needed) {
        sentinel_kernel<<<(out_size + 255) / 256, 256, 0, stream>>>(out, out_size);
        return;
    }
    unsigned long long* mbT = (unsigned long long*)(ws + shorts_main);
    unsigned short* wsW  = ws + (size_t)3 * HN * NN * DD;           // scratch in ao region
    unsigned short* lastb = wsW + (size_t)3 * HN * DD * DD;         // t==3 slot
    unsigned short* qkvb = wsW + (size_t)4 * HN * DD * DD;          // after 4 tensors

    prep_kernel<<<dim3(4096 + 64 + 96), 256, 0, stream>>>(mask, mbT, out, out_size,
                                                          Qw, Kw, Vw, last, q, k, v,
                                                          wsW, qkvb);
    proj6_kernel<<<dim3(32, 16, 3), 256, 0, stream>>>(qkvb, wsW, ws);
    attn_kernel<<<dim3(512), 256, 0, stream>>>(ws, mbT, lastb, out);
}